// Round 1
// baseline (476.402 us; speedup 1.0000x reference)
//
#include <hip/hip_runtime.h>
#include <hip/hip_bf16.h>

#define N 8192
#define FIN 512
#define FOUT 64
#define ALPHA 0.2f

typedef __bf16 bf16x8 __attribute__((ext_vector_type(8)));
typedef float f32x4 __attribute__((ext_vector_type(4)));

// ---- workspace layout (bytes) ----
// [0,       32768) : lsum  (N floats, softmax denominators; atomicAdd targets)
// [32768,   32772) : Mkey  (ordered-uint global max of f_dst)
// [65536,   98304) : f_src (N floats)
// [98304,  131072) : f_dst (N floats)
// [131072, 1179648): hT    (bf16 [FOUT][N], h transposed for B-fragments)

__device__ __forceinline__ unsigned enc_f(float x) {
    unsigned u = __float_as_uint(x);
    return (u & 0x80000000u) ? ~u : (u | 0x80000000u);
}
__device__ __forceinline__ float dec_f(unsigned u) {
    return (u & 0x80000000u) ? __uint_as_float(u & 0x7FFFFFFFu) : __uint_as_float(~u);
}

// ---------------- Kernel 1: h = input @ W  (bf16 MFMA, fp32 accum) --------
// block = 256 thr (4 waves), each wave a 16-row M-tile; 64 rows/block.
__global__ __launch_bounds__(256) void k1_hgemm(const float* __restrict__ in,
                                                const float* __restrict__ W,
                                                float* __restrict__ h) {
    const int wave = threadIdx.x >> 6;
    const int lane = threadIdx.x & 63;
    const int m = lane & 15, quad = lane >> 4;
    const int i0 = blockIdx.x * 64 + wave * 16;

    f32x4 acc[4];
#pragma unroll
    for (int t = 0; t < 4; ++t) acc[t] = (f32x4){0.f, 0.f, 0.f, 0.f};

    const float* arow = in + (size_t)(i0 + m) * FIN;
    for (int k0 = 0; k0 < FIN; k0 += 32) {
        const float4 a0 = *(const float4*)(arow + k0 + quad * 8);
        const float4 a1 = *(const float4*)(arow + k0 + quad * 8 + 4);
        bf16x8 af;
        af[0] = (__bf16)a0.x; af[1] = (__bf16)a0.y; af[2] = (__bf16)a0.z; af[3] = (__bf16)a0.w;
        af[4] = (__bf16)a1.x; af[5] = (__bf16)a1.y; af[6] = (__bf16)a1.z; af[7] = (__bf16)a1.w;
#pragma unroll
        for (int t = 0; t < 4; ++t) {
            bf16x8 bf;
#pragma unroll
            for (int jj = 0; jj < 8; ++jj)
                bf[jj] = (__bf16)W[(k0 + quad * 8 + jj) * FOUT + t * 16 + m];
            acc[t] = __builtin_amdgcn_mfma_f32_16x16x32_bf16(af, bf, acc[t], 0, 0, 0);
        }
    }
    // C/D: col = lane&15, row = quad*4 + reg
#pragma unroll
    for (int t = 0; t < 4; ++t)
#pragma unroll
        for (int r = 0; r < 4; ++r)
            h[(size_t)(i0 + quad * 4 + r) * FOUT + t * 16 + m] = acc[t][r];
}

// ---------------- Kernel 2: f_src/f_dst = h@a1, h@a2; hT = bf16(h)^T; M ---
__global__ __launch_bounds__(256) void k2_prep(const float* __restrict__ h,
                                               const float* __restrict__ a,
                                               float* __restrict__ f_src,
                                               float* __restrict__ f_dst,
                                               unsigned* __restrict__ Mkey,
                                               __bf16* __restrict__ hT) {
    const int wave = threadIdx.x >> 6;
    const int lane = threadIdx.x & 63;
    const int base = blockIdx.x * 64 + wave * 16;
    const float a1 = a[lane], a2 = a[64 + lane];
    float localM = -1e30f;
    for (int rr = 0; rr < 16; ++rr) {
        const int i = base + rr;
        const float v = h[(size_t)i * FOUT + lane];
        hT[(size_t)lane * N + i] = (__bf16)v;
        float s1 = v * a1, s2 = v * a2;
#pragma unroll
        for (int off = 32; off > 0; off >>= 1) {
            s1 += __shfl_xor(s1, off);
            s2 += __shfl_xor(s2, off);
        }
        if (lane == 0) {
            f_src[i] = s1;
            f_dst[i] = s2;
            if (s2 > localM) localM = s2;
        }
    }
    if (lane == 0) atomicMax(Mkey, enc_f(localM));
}

// ---------------- Kernel 3: fused mask+softmax-weights+PV (HBM-bound) -----
// 1 wave/block, 16-row M-tile, j split into NCHUNK chunks; atomics into num/lsum.
constexpr int NCHUNK = 8;
constexpr int JLEN = N / NCHUNK;  // 1024

__global__ __launch_bounds__(64) void k3_attn(const int* __restrict__ adj,
                                              const float* __restrict__ f_src,
                                              const float* __restrict__ f_dst,
                                              const unsigned* __restrict__ Mkey,
                                              const __bf16* __restrict__ hT,
                                              float* __restrict__ num,
                                              float* __restrict__ lsum) {
    const int lane = threadIdx.x;
    const int m = lane & 15, quad = lane >> 4;
    const int i0 = blockIdx.x * 16;
    const int jstart = blockIdx.y * JLEN;
    const float LOG2E = 1.44269504088896f;

    const float M = dec_f(*Mkey);
    const float fs = f_src[i0 + m];
    const float t0 = fs + M;
    const float shift = t0 > 0.f ? t0 : ALPHA * t0;  // leaky(fs + max f_dst) >= every e

    f32x4 acc[4];
#pragma unroll
    for (int t = 0; t < 4; ++t) acc[t] = (f32x4){0.f, 0.f, 0.f, 0.f};
    f32x4 accl = (f32x4){0.f, 0.f, 0.f, 0.f};

    bf16x8 bones;  // B[k][n] = (n==0) -> row-sum column
#pragma unroll
    for (int jj = 0; jj < 8; ++jj) bones[jj] = (__bf16)(m == 0 ? 1.0f : 0.0f);

    const int* arow = adj + (size_t)(i0 + m) * N;
    for (int j0 = jstart; j0 < jstart + JLEN; j0 += 32) {
        const int4 A0 = *(const int4*)(arow + j0 + quad * 8);
        const int4 A1 = *(const int4*)(arow + j0 + quad * 8 + 4);
        const float4 d0 = *(const float4*)(f_dst + j0 + quad * 8);
        const float4 d1 = *(const float4*)(f_dst + j0 + quad * 8 + 4);

        float wv[8];
        {
            const int am[8] = {A0.x, A0.y, A0.z, A0.w, A1.x, A1.y, A1.z, A1.w};
            const float fd[8] = {d0.x, d0.y, d0.z, d0.w, d1.x, d1.y, d1.z, d1.w};
#pragma unroll
            for (int jj = 0; jj < 8; ++jj) {
                float e = fs + fd[jj];
                e = e > 0.f ? e : ALPHA * e;
                const float ex = __builtin_amdgcn_exp2f((e - shift) * LOG2E);
                wv[jj] = am[jj] > 0 ? ex : 0.f;
            }
        }
        bf16x8 af;
#pragma unroll
        for (int jj = 0; jj < 8; ++jj) af[jj] = (__bf16)wv[jj];

#pragma unroll
        for (int t = 0; t < 4; ++t) {
            const bf16x8 bfr = *(const bf16x8*)(hT + (size_t)(t * 16 + m) * N + j0 + quad * 8);
            acc[t] = __builtin_amdgcn_mfma_f32_16x16x32_bf16(af, bfr, acc[t], 0, 0, 0);
        }
        accl = __builtin_amdgcn_mfma_f32_16x16x32_bf16(af, bones, accl, 0, 0, 0);
    }

    // C/D: col = lane&15, row = quad*4 + reg
#pragma unroll
    for (int t = 0; t < 4; ++t)
#pragma unroll
        for (int r = 0; r < 4; ++r)
            atomicAdd(&num[(size_t)(i0 + quad * 4 + r) * FOUT + t * 16 + m], acc[t][r]);
    if (m == 0) {
#pragma unroll
        for (int r = 0; r < 4; ++r) atomicAdd(&lsum[i0 + quad * 4 + r], accl[r]);
    }
}

// ---------------- Kernel 4: out = leaky(num / lsum, 0.01) -----------------
__global__ __launch_bounds__(256) void k4_norm(float* __restrict__ out,
                                               const float* __restrict__ lsum) {
    const int idx = blockIdx.x * 256 + threadIdx.x;
    const float l = lsum[idx >> 6];
    const float v = out[idx] / (l > 0.f ? l : 1.f);
    out[idx] = v > 0.f ? v : 0.01f * v;
}

extern "C" void kernel_launch(void* const* d_in, const int* in_sizes, int n_in,
                              void* d_out, int out_size, void* d_ws, size_t ws_size,
                              hipStream_t stream) {
    const float* in = (const float*)d_in[0];
    const int* adj = (const int*)d_in[1];
    const float* W = (const float*)d_in[2];
    const float* a = (const float*)d_in[3];
    float* out = (float*)d_out;

    char* ws = (char*)d_ws;
    float* lsum = (float*)ws;
    unsigned* Mkey = (unsigned*)(ws + 32768);
    float* f_src = (float*)(ws + 65536);
    float* f_dst = (float*)(ws + 98304);
    __bf16* hT = (__bf16*)(ws + 131072);

    // zero lsum + Mkey (ordered-uint 0 acts as -inf)
    hipMemsetAsync(ws, 0, 32772, stream);

    // h (fp32) staged in d_out, consumed by k2, then d_out reused as numerator
    k1_hgemm<<<N / 64, 256, 0, stream>>>(in, W, out);
    k2_prep<<<N / 64, 256, 0, stream>>>(out, a, f_src, f_dst, Mkey, hT);
    hipMemsetAsync(d_out, 0, (size_t)N * FOUT * sizeof(float), stream);

    dim3 g3(N / 16, NCHUNK);
    k3_attn<<<g3, 64, 0, stream>>>(adj, f_src, f_dst, Mkey, hT, out, lsum);
    k4_norm<<<(N * FOUT) / 256, 256, 0, stream>>>(out, lsum);
}

// Round 2
// 418.753 us; speedup vs baseline: 1.1377x; 1.1377x over previous
//
#include <hip/hip_runtime.h>
#include <hip/hip_bf16.h>

#define N 8192
#define FIN 512
#define FOUT 64
#define ALPHA 0.2f

typedef __bf16 bf16x8 __attribute__((ext_vector_type(8)));
typedef float f32x4 __attribute__((ext_vector_type(4)));
typedef int i32x4 __attribute__((ext_vector_type(4)));

// ---- workspace layout (bytes) ----
// [0,64)            : Mkey (ordered-uint global max of f_dst)
// [64, 32832)       : lsum (N floats)
// [32832, 65600)    : f_src (N floats)
// [65600, 98368)    : f_dst (N floats)
// [98368, 163904)   : WtG  (bf16 [FOUT][FIN], W transposed)
// [163904, 1212480) : hT   (bf16 [FOUT][N], h transposed)

__device__ __forceinline__ unsigned enc_f(float x) {
    unsigned u = __float_as_uint(x);
    return (u & 0x80000000u) ? ~u : (u | 0x80000000u);
}
__device__ __forceinline__ float dec_f(unsigned u) {
    return (u & 0x80000000u) ? __uint_as_float(u & 0x7FFFFFFFu) : __uint_as_float(~u);
}

// ---------- k_wt: WtG[f][k] = bf16(W[k][f]) --------------------------------
__global__ __launch_bounds__(64) void k_wt(const float* __restrict__ W,
                                           __bf16* __restrict__ WtG) {
    const int g = blockIdx.x * 64 + threadIdx.x;  // 0..4095
    const int k = g >> 3;
    const int f0 = (g & 7) * 8;
    const float4 w0 = *(const float4*)(W + (size_t)k * FOUT + f0);
    const float4 w1 = *(const float4*)(W + (size_t)k * FOUT + f0 + 4);
    WtG[(size_t)(f0 + 0) * FIN + k] = (__bf16)w0.x;
    WtG[(size_t)(f0 + 1) * FIN + k] = (__bf16)w0.y;
    WtG[(size_t)(f0 + 2) * FIN + k] = (__bf16)w0.z;
    WtG[(size_t)(f0 + 3) * FIN + k] = (__bf16)w0.w;
    WtG[(size_t)(f0 + 4) * FIN + k] = (__bf16)w1.x;
    WtG[(size_t)(f0 + 5) * FIN + k] = (__bf16)w1.y;
    WtG[(size_t)(f0 + 6) * FIN + k] = (__bf16)w1.z;
    WtG[(size_t)(f0 + 7) * FIN + k] = (__bf16)w1.w;
}

// ---------- k12: h=in@W (MFMA) -> f_src/f_dst/Mkey + hT (fused) ------------
// 1 wave per block, 16 rows; 512 blocks.
__global__ __launch_bounds__(64) void k12(const float* __restrict__ in,
                                          const __bf16* __restrict__ WtG,
                                          const float* __restrict__ a,
                                          float* __restrict__ f_src,
                                          float* __restrict__ f_dst,
                                          unsigned* __restrict__ Mkey,
                                          __bf16* __restrict__ hT) {
    __shared__ __bf16 tb[64][16];
    const int lane = threadIdx.x;
    const int m = lane & 15, quad = lane >> 4;
    const int i0 = blockIdx.x * 16;

    f32x4 acc[4];
#pragma unroll
    for (int t = 0; t < 4; ++t) acc[t] = (f32x4){0.f, 0.f, 0.f, 0.f};

    const float* arow = in + (size_t)(i0 + m) * FIN + quad * 8;
    for (int k0 = 0; k0 < FIN; k0 += 32) {
        const float4 x0 = *(const float4*)(arow + k0);
        const float4 x1 = *(const float4*)(arow + k0 + 4);
        bf16x8 af;
        af[0] = (__bf16)x0.x; af[1] = (__bf16)x0.y; af[2] = (__bf16)x0.z; af[3] = (__bf16)x0.w;
        af[4] = (__bf16)x1.x; af[5] = (__bf16)x1.y; af[6] = (__bf16)x1.z; af[7] = (__bf16)x1.w;
#pragma unroll
        for (int t = 0; t < 4; ++t) {
            const bf16x8 bf = *(const bf16x8*)(WtG + (size_t)(t * 16 + m) * FIN + k0 + quad * 8);
            acc[t] = __builtin_amdgcn_mfma_f32_16x16x32_bf16(af, bf, acc[t], 0, 0, 0);
        }
    }
    // f_src / f_dst: dot rows with a1/a2, reduce across the 16 m-lanes of each quad
    float s1[4], s2[4];
#pragma unroll
    for (int r = 0; r < 4; ++r) { s1[r] = 0.f; s2[r] = 0.f; }
#pragma unroll
    for (int t = 0; t < 4; ++t) {
        const float a1 = a[t * 16 + m], a2 = a[64 + t * 16 + m];
#pragma unroll
        for (int r = 0; r < 4; ++r) {
            s1[r] += acc[t][r] * a1;
            s2[r] += acc[t][r] * a2;
        }
    }
#pragma unroll
    for (int off = 1; off <= 8; off <<= 1)
#pragma unroll
        for (int r = 0; r < 4; ++r) {
            s1[r] += __shfl_xor(s1[r], off);
            s2[r] += __shfl_xor(s2[r], off);
        }
    float lm = -1e30f;
    if (m == 0) {
#pragma unroll
        for (int r = 0; r < 4; ++r) {
            f_src[i0 + quad * 4 + r] = s1[r];
            f_dst[i0 + quad * 4 + r] = s2[r];
            lm = fmaxf(lm, s2[r]);
        }
    }
    lm = fmaxf(lm, __shfl_xor(lm, 16));
    lm = fmaxf(lm, __shfl_xor(lm, 32));
    if (lane == 0) atomicMax(Mkey, enc_f(lm));

    // hT via LDS transpose, coalesced 16B stores
#pragma unroll
    for (int t = 0; t < 4; ++t)
#pragma unroll
        for (int r = 0; r < 4; ++r) tb[t * 16 + m][quad * 4 + r] = (__bf16)acc[t][r];
    __syncthreads();
    {
        const int f = lane;
        const bf16x8 v0 = *(const bf16x8*)&tb[f][0];
        const bf16x8 v1 = *(const bf16x8*)&tb[f][8];
        *(bf16x8*)(hT + (size_t)f * N + i0) = v0;
        *(bf16x8*)(hT + (size_t)f * N + i0 + 8) = v1;
    }
}

// ---------- k3: fused mask+softmax-weight+PV, hT/f_dst LDS-staged ----------
constexpr int JT = 256;  // j-tile width held in LDS

__global__ __launch_bounds__(256, 4) void k3_attn(const int* __restrict__ adj,
                                                  const float* __restrict__ f_src,
                                                  const float* __restrict__ fdstG,
                                                  const unsigned* __restrict__ Mkey,
                                                  const __bf16* __restrict__ hT,
                                                  float* __restrict__ num,
                                                  float* __restrict__ lsum) {
    __shared__ __bf16 sh[64][JT + 8];  // 33,792 B (pad keeps b128 reads even)
    __shared__ float sfd[JT];          // 1 KB
    const int tid = threadIdx.x;
    const int wv = tid >> 6, lane = tid & 63;
    const int m = lane & 15, quad = lane >> 4;
    const int i0 = blockIdx.x * 64 + wv * 16;
    const int jbase = blockIdx.y * 1024;
    const float LOG2E = 1.44269504088896f;

    const float M = dec_f(*Mkey);
    const float fs = f_src[i0 + m];
    const float t0 = fs + M;
    const float shift = fmaxf(t0, ALPHA * t0);  // leaky(fs + max f_dst)

    f32x4 acc[4];
#pragma unroll
    for (int t = 0; t < 4; ++t) acc[t] = (f32x4){0.f, 0.f, 0.f, 0.f};
    f32x4 accl = (f32x4){0.f, 0.f, 0.f, 0.f};

    bf16x8 bones;  // ones-column B: row-sums for the denominator
#pragma unroll
    for (int jj = 0; jj < 8; ++jj) bones[jj] = (__bf16)(m == 0 ? 1.0f : 0.0f);

    const int* arow = adj + (size_t)(i0 + m) * N;

    for (int jt = jbase; jt < jbase + 1024; jt += JT) {
        __syncthreads();
        // stage hT[:, jt:jt+256] (32 KB) cooperatively
#pragma unroll
        for (int c = tid; c < 64 * JT / 8; c += 256) {
            const int f = c >> 5, off = (c & 31) * 8;
            *(bf16x8*)&sh[f][off] = *(const bf16x8*)(hT + (size_t)f * N + jt + off);
        }
        if (tid < 64) *(f32x4*)&sfd[tid * 4] = *(const f32x4*)(fdstG + jt + tid * 4);
        __syncthreads();

#pragma unroll
        for (int jj0 = 0; jj0 < JT; jj0 += 64) {
            // batch adj loads (nontemporal: don't evict L2-hot hT/f_dst)
            const int* p = arow + jt + jj0 + quad * 8;
            i32x4 A[4];
            A[0] = __builtin_nontemporal_load((const i32x4*)p);
            A[1] = __builtin_nontemporal_load((const i32x4*)(p + 4));
            A[2] = __builtin_nontemporal_load((const i32x4*)(p + 32));
            A[3] = __builtin_nontemporal_load((const i32x4*)(p + 36));
            const f32x4 D0 = *(const f32x4*)&sfd[jj0 + quad * 8];
            const f32x4 D1 = *(const f32x4*)&sfd[jj0 + quad * 8 + 4];
            const f32x4 D2 = *(const f32x4*)&sfd[jj0 + 32 + quad * 8];
            const f32x4 D3 = *(const f32x4*)&sfd[jj0 + 32 + quad * 8 + 4];
#pragma unroll
            for (int u = 0; u < 2; ++u) {
                const i32x4 Aa = A[u * 2], Ab = A[u * 2 + 1];
                const f32x4 Da = u ? D2 : D0, Db = u ? D3 : D1;
                float wvv[8];
#pragma unroll
                for (int jj = 0; jj < 8; ++jj) {
                    const float fd = jj < 4 ? Da[jj] : Db[jj - 4];
                    const int am = jj < 4 ? Aa[jj] : Ab[jj - 4];
                    float e = fs + fd;
                    e = fmaxf(e, ALPHA * e);
                    const float ex = __builtin_amdgcn_exp2f((e - shift) * LOG2E);
                    wvv[jj] = am > 0 ? ex : 0.f;
                }
                bf16x8 af;
#pragma unroll
                for (int jj = 0; jj < 8; ++jj) af[jj] = (__bf16)wvv[jj];
#pragma unroll
                for (int t = 0; t < 4; ++t) {
                    const bf16x8 bfr =
                        *(const bf16x8*)&sh[t * 16 + m][jj0 + u * 32 + quad * 8];
                    acc[t] = __builtin_amdgcn_mfma_f32_16x16x32_bf16(af, bfr, acc[t], 0, 0, 0);
                }
                accl = __builtin_amdgcn_mfma_f32_16x16x32_bf16(af, bones, accl, 0, 0, 0);
            }
        }
    }
    // epilogue: C/D col=lane&15, row=quad*4+reg
#pragma unroll
    for (int t = 0; t < 4; ++t)
#pragma unroll
        for (int r = 0; r < 4; ++r)
            atomicAdd(&num[(size_t)(i0 + quad * 4 + r) * FOUT + t * 16 + m], acc[t][r]);
    if (m == 0) {
#pragma unroll
        for (int r = 0; r < 4; ++r) atomicAdd(&lsum[i0 + quad * 4 + r], accl[r]);
    }
}

// ---------- k4: out = leaky(num / lsum, 0.01) ------------------------------
__global__ __launch_bounds__(256) void k4_norm(float* __restrict__ out,
                                               const float* __restrict__ lsum) {
    const int idx = blockIdx.x * 256 + threadIdx.x;
    const float l = lsum[idx >> 6];
    const float v = out[idx] / (l > 0.f ? l : 1.f);
    out[idx] = v > 0.f ? v : 0.01f * v;
}

extern "C" void kernel_launch(void* const* d_in, const int* in_sizes, int n_in,
                              void* d_out, int out_size, void* d_ws, size_t ws_size,
                              hipStream_t stream) {
    const float* in = (const float*)d_in[0];
    const int* adj = (const int*)d_in[1];
    const float* W = (const float*)d_in[2];
    const float* a = (const float*)d_in[3];
    float* out = (float*)d_out;

    char* ws = (char*)d_ws;
    unsigned* Mkey = (unsigned*)ws;
    float* lsum = (float*)(ws + 64);
    float* f_src = (float*)(ws + 32832);
    float* f_dst = (float*)(ws + 65600);
    __bf16* WtG = (__bf16*)(ws + 98368);
    __bf16* hT = (__bf16*)(ws + 163904);

    hipMemsetAsync(ws, 0, 64 + N * 4, stream);                      // Mkey + lsum
    hipMemsetAsync(d_out, 0, (size_t)N * FOUT * sizeof(float), stream);  // num

    k_wt<<<64, 64, 0, stream>>>(W, WtG);
    k12<<<N / 16, 64, 0, stream>>>(in, WtG, a, f_src, f_dst, Mkey, hT);

    dim3 g3(N / 64, 8);
    k3_attn<<<g3, 256, 0, stream>>>(adj, f_src, f_dst, Mkey, hT, out, lsum);
    k4_norm<<<(N * FOUT) / 256, 256, 0, stream>>>(out, lsum);
}